// Round 11
// baseline (180.636 us; speedup 1.0000x reference)
//
#include <hip/hip_runtime.h>
#include <hip/hip_bf16.h>
#include <cstddef>

typedef short short8 __attribute__((ext_vector_type(8)));
typedef short short4v __attribute__((ext_vector_type(4)));
typedef short short2v __attribute__((ext_vector_type(2)));
typedef int   int2v  __attribute__((ext_vector_type(2)));
typedef int   int4v  __attribute__((ext_vector_type(4)));
typedef float f32x4  __attribute__((ext_vector_type(4)));
typedef __hip_bfloat16 bf;

#define DEV __device__ __forceinline__

DEV float bf2f(unsigned short u) {
  unsigned int x = ((unsigned int)u) << 16;
  float f; __builtin_memcpy(&f, &x, 4); return f;
}
DEV unsigned int fbits(float v) {
  unsigned int u; __builtin_memcpy(&u, &v, 4); return u;
}
// pack two f32 -> one dword of two bf16 (truncation), hi:lo
DEV unsigned int pack2(float hi, float lo) {
  return __builtin_amdgcn_perm(fbits(hi), fbits(lo), 0x07060302u);
}
DEV float exp2_fast(float x) {
#if __has_builtin(__builtin_amdgcn_exp2f)
  return __builtin_amdgcn_exp2f(x);
#else
  return exp2f(x);
#endif
}
DEV float fast_tanh(float x) {
  float e2 = __expf(2.0f * x);
  return 1.0f - 2.0f * __builtin_amdgcn_rcpf(e2 + 1.0f);
}

// ============ K0: weight prep: WaFrag (pre-permuted bf16) + 7 transposes ==
__global__ void k_prep(const float* __restrict__ Wa, const float* __restrict__ Wt1,
                       const float* __restrict__ Wt2, const float* __restrict__ WaM,
                       const float* __restrict__ Wpa, const float* __restrict__ Wpn,
                       const float* __restrict__ WpaM, const float* __restrict__ WpnM,
                       bf* __restrict__ WaFrag, float* __restrict__ WtT1,
                       float* __restrict__ WtT2, float* __restrict__ WaMT,
                       float* __restrict__ WpaT, float* __restrict__ WpnT,
                       float* __restrict__ WpaMT, float* __restrict__ WpnMT) {
  int mat = blockIdx.x >> 6;
  int idx = (blockIdx.x & 63) * 256 + threadIdx.x;  // 0..16383
  if (mat == 0) {
    // fragment order: chunk c = (kt*4+ds)*64 + lane, element u in 0..7
    int c = idx >> 3, u = idx & 7;
    int kt = c >> 8, ds = (c >> 6) & 3, L = c & 63;
    int l15 = L & 15, q = L >> 4;
    int d = ds * 32 + q * 8 + u;
    int k = kt * 16 + l15;
    WaFrag[idx] = __float2bfloat16(Wa[d * 128 + k]);
    return;
  }
  int d = idx >> 7, k = idx & 127;
  const float* src;
  switch (mat) {
    case 1: src = Wt1; break;  case 2: src = Wt2; break;
    case 3: src = WaM; break;  case 4: src = Wpa; break;
    case 5: src = Wpn; break;  case 6: src = WpaM; break;
    default: src = WpnM; break;
  }
  float v = src[d * 128 + k];
  float* dst;
  switch (mat) {
    case 1: dst = WtT1; break;  case 2: dst = WtT2; break;
    case 3: dst = WaMT; break;  case 4: dst = WpaT; break;
    case 5: dst = WpnT; break;  case 6: dst = WpaMT; break;
    default: dst = WpnMT; break;
  }
  dst[k * 128 + d] = v;
}

// ============ K1: projection -> Xbf (row-major) + XbfT (col-major) ========
__global__ void __launch_bounds__(256) k_proj(
    const float* __restrict__ x1, const float* __restrict__ x2,
    const float* __restrict__ WtT1, const float* __restrict__ bt1,
    const float* __restrict__ WtT2, const float* __restrict__ bt2,
    bf* __restrict__ Xbf, bf* __restrict__ XbfT) {
  int b = blockIdx.x >> 4, g = blockIdx.x & 15;
  int ibase = g * 16;
  bool side1 = ibase < 128;
  const float* Wt = side1 ? WtT1 : WtT2;
  const float* bt = side1 ? bt1 : bt2;
  const float* xs = side1 ? (x1 + ((size_t)b * 128 + ibase) * 128)
                          : (x2 + ((size_t)b * 128 + (ibase - 128)) * 128);
  __shared__ float rowz[16][128];
  int t = threadIdx.x;
  {
    int i = t >> 4, dg = t & 15;
    const f32x4* p = (const f32x4*)(xs + i * 128 + dg * 8);
    *(f32x4*)&rowz[i][dg * 8] = p[0];
    *(f32x4*)&rowz[i][dg * 8 + 4] = p[1];
  }
  __syncthreads();
  int k = t & 127, ih = t >> 7;
  float acc[8];
  float bb = bt[k];
#pragma unroll
  for (int m = 0; m < 8; ++m) acc[m] = bb;
  const f32x4* wrow = (const f32x4*)(Wt + k * 128);
#pragma unroll 4
  for (int c = 0; c < 32; ++c) {
    f32x4 w4 = wrow[c];
#pragma unroll
    for (int m = 0; m < 8; ++m) {
      const float* r = &rowz[ih * 8 + m][c * 4];
      acc[m] += r[0] * w4[0] + r[1] * w4[1] + r[2] * w4[2] + r[3] * w4[3];
    }
  }
#pragma unroll
  for (int m = 0; m < 8; ++m)
    Xbf[((size_t)b * 256 + ibase + ih * 8 + m) * 128 + k] = __float2bfloat16(acc[m]);
  int4v tv;
  tv[0] = (int)pack2(acc[1], acc[0]);
  tv[1] = (int)pack2(acc[3], acc[2]);
  tv[2] = (int)pack2(acc[5], acc[4]);
  tv[3] = (int)pack2(acc[7], acc[6]);
  *(int4v*)(XbfT + (size_t)b * 32768 + (size_t)k * 256 + ibase + ih * 8) = tv;
}

// ============ K2: master mean + attention scores sM[b,n] ==================
__global__ void __launch_bounds__(256) k_mscore(
    const bf* __restrict__ Xbf,
    const float* __restrict__ WaMT, const float* __restrict__ baM,
    const float* __restrict__ wM, float* __restrict__ sM,
    float* __restrict__ masterf) {
  int b = blockIdx.x >> 4, g = blockIdx.x & 15;
  int nbase = g * 16;
  int t = threadIdx.x;
  __shared__ float red[16][128];
  __shared__ float masterv[128];
  __shared__ float z[16][128];
  {
    int dg = t & 15, rl = t >> 4;
    float part[8];
#pragma unroll
    for (int u = 0; u < 8; ++u) part[u] = 0.0f;
    for (int r = rl; r < 256; r += 16) {
      short8 xr = *(const short8*)(Xbf + ((size_t)b * 256 + r) * 128 + dg * 8);
#pragma unroll
      for (int u = 0; u < 8; ++u) part[u] += bf2f((unsigned short)xr[u]);
    }
#pragma unroll
    for (int u = 0; u < 8; ++u) red[rl][dg * 8 + u] = part[u];
  }
  __syncthreads();
  if (t < 128) {
    float s = 0.0f;
#pragma unroll
    for (int j = 0; j < 16; ++j) s += red[j][t];
    s *= (1.0f / 256.0f);
    masterv[t] = s;
    if (g == 0) masterf[b * 128 + t] = s;
  }
  __syncthreads();
  {
    int n = t >> 4, dg = t & 15;
    short8 xr = *(const short8*)(Xbf + ((size_t)b * 256 + nbase + n) * 128 + dg * 8);
#pragma unroll
    for (int u = 0; u < 8; ++u)
      z[n][dg * 8 + u] = bf2f((unsigned short)xr[u]) * masterv[dg * 8 + u];
  }
  __syncthreads();
  int k = t & 127, nh = t >> 7;
  float acc[8];
  float bb = baM[k];
#pragma unroll
  for (int m = 0; m < 8; ++m) acc[m] = bb;
  const f32x4* wrow = (const f32x4*)(WaMT + k * 128);
#pragma unroll 4
  for (int c = 0; c < 32; ++c) {
    f32x4 w4 = wrow[c];
#pragma unroll
    for (int m = 0; m < 8; ++m) {
      const float* zr = &z[nh * 8 + m][c * 4];
      acc[m] += zr[0] * w4[0] + zr[1] * w4[1] + zr[2] * w4[2] + zr[3] * w4[3];
    }
  }
  float wk = wM[k];
  __syncthreads();
#pragma unroll
  for (int m = 0; m < 8; ++m) red[nh * 8 + m][k] = fast_tanh(acc[m]) * wk;
  __syncthreads();
  int n2 = t >> 4, kl = t & 15;
  float s = 0.0f;
#pragma unroll
  for (int c = 0; c < 8; ++c) s += red[n2][kl + c * 16];
  s += __shfl_xor(s, 1, 16);
  s += __shfl_xor(s, 2, 16);
  s += __shfl_xor(s, 4, 16);
  s += __shfl_xor(s, 8, 16);
  if (kl == 0) sM[b * 256 + nbase + n2] = s;
}

// ============ K3: fused scores + softmax + agg + heads (+ master out) =====
// grid = 8b x 64ig = 512 blocks, 256 thr (4 waves). Block: 4 i x 256 j.
// All 4 i processed per MFMA group: each Bf ds_read feeds 4 independent
// MFMAs (round 10's 2:1 read:MFMA chain was the stall; VGPR was only 88).
__global__ void __launch_bounds__(256, 2) k_fused(
    const bf* __restrict__ Xbf, const bf* __restrict__ XbfT,
    const bf* __restrict__ WaFrag,
    const float* __restrict__ ba, const float* __restrict__ w11,
    const float* __restrict__ w22, const float* __restrict__ w12,
    const float* __restrict__ WpaT, const float* __restrict__ bpa,
    const float* __restrict__ WpnT, const float* __restrict__ bpn,
    const float* __restrict__ gamma, const float* __restrict__ beta,
    const float* __restrict__ sM, const float* __restrict__ masterf,
    const float* __restrict__ WpaMT, const float* __restrict__ bpaM,
    const float* __restrict__ WpnMT, const float* __restrict__ bpnM,
    float* __restrict__ dout) {
  int b = blockIdx.x >> 6, ig = blockIdx.x & 63;
  int ibase = ig * 4;
  int t = threadIdx.x, wave = t >> 6, lane = t & 63, l15 = lane & 15, quad = lane >> 4;

  // hand-carved LDS (49,728 B): wfrag region reused by phase E overlay
  __shared__ __align__(16) char smem[49728];
  unsigned short* wfrag = (unsigned short*)smem;                       // 32768
  float (*xif)[132] = (float(*)[132])(smem + 32768);                   // 2112
  unsigned short (*scl)[264] = (unsigned short(*)[264])(smem + 34880); // 2112
  unsigned short (*pl)[264] = (unsigned short(*)[264])(smem + 36992);  // 8448
  float (*aggl)[132] = (float(*)[132])(smem + 45440);                  // 4224
  float* rinv = (float*)(smem + 49664);                                // 64

  // stage Wa fragments (coalesced 16 B/lane)
#pragma unroll
  for (int c = 0; c < 8; ++c) {
    int idx = c * 256 + t;
    *(short8*)&wfrag[idx * 8] = *(const short8*)(WaFrag + (size_t)idx * 8);
  }
  // stage x_i rows unpacked to f32 (4 rows x 128)
  {
    int ii = t >> 6, dg = t & 63;
    short2v xr = *(const short2v*)(Xbf + ((size_t)(b * 256 + ibase + ii)) * 128 + dg * 2);
    xif[ii][dg * 2] = bf2f((unsigned short)xr[0]);
    xif[ii][dg * 2 + 1] = bf2f((unsigned short)xr[1]);
  }
  // zero MFMA pad: pl rows 4..15 (cols 0..255) and rinv[4..15]
  {
    int4v zz = {0, 0, 0, 0};
    int r0 = 4 + (t >> 5), c0 = (t & 31) * 8;
    *(int4v*)&pl[r0][c0] = zz;
    if (t < 128) *(int4v*)&pl[4 + ((t + 256) >> 5)][((t + 256) & 31) * 8] = zz;
    if (t < 12) rinv[4 + t] = 0.0f;
  }

  bool side1 = ig < 32;
  const float C2L = 2.8853900817779268f;  // 2*log2(e)
  float tb[8];
#pragma unroll
  for (int kt = 0; kt < 8; ++kt) tb[kt] = ba[kt * 16 + l15] * C2L;
  __syncthreads();

  // -------- phase A: scores for 4 i x 256 j (wave owns 16 j per pass) ----
  for (int jt = 0; jt < 4; ++jt) {
    int j0 = jt * 64 + wave * 16;
    const float* wv = side1 ? (jt < 2 ? w11 : w12) : (jt < 2 ? w12 : w22);
    float w2s[8], wls = 0.0f;
#pragma unroll
    for (int kt = 0; kt < 8; ++kt) {
      float w = wv[kt * 16 + l15];
      w2s[kt] = 2.0f * w;
      wls += w;
    }
    float Afm[4][8];
#pragma unroll
    for (int ds = 0; ds < 4; ++ds) {
      short8 a = *(const short8*)(Xbf + ((size_t)(b * 256 + j0 + l15)) * 128 + ds * 32 + quad * 8);
#pragma unroll
      for (int u = 0; u < 8; ++u) Afm[ds][u] = bf2f((unsigned short)a[u]);
    }
    // pack scaled-A for all 4 i
    short8 sa[4][4];
#pragma unroll
    for (int i2 = 0; i2 < 4; ++i2)
#pragma unroll
      for (int ds = 0; ds < 4; ++ds) {
        const f32x4* xp = (const f32x4*)&xif[i2][ds * 32 + quad * 8];
        f32x4 x0 = xp[0], x1 = xp[1];
        int4v pk;
        pk[0] = (int)pack2(Afm[ds][1] * x0[1], Afm[ds][0] * x0[0]);
        pk[1] = (int)pack2(Afm[ds][3] * x0[3], Afm[ds][2] * x0[2]);
        pk[2] = (int)pack2(Afm[ds][5] * x1[1], Afm[ds][4] * x1[0]);
        pk[3] = (int)pack2(Afm[ds][7] * x1[3], Afm[ds][6] * x1[2]);
        sa[i2][ds] = __builtin_bit_cast(short8, pk);
      }
    // MFMA: each Bf read feeds 4 independent accumulation chains
    f32x4 acc[4][8];
#pragma unroll
    for (int i2 = 0; i2 < 4; ++i2)
#pragma unroll
      for (int kt = 0; kt < 8; ++kt) { f32x4 z = {0.f, 0.f, 0.f, 0.f}; acc[i2][kt] = z; }
#pragma unroll
    for (int kt = 0; kt < 8; ++kt)
#pragma unroll
      for (int ds = 0; ds < 4; ++ds) {
        short8 Bf = *(const short8*)&wfrag[((kt * 4 + ds) * 64 + lane) * 8];
        acc[0][kt] = __builtin_amdgcn_mfma_f32_16x16x32_bf16(sa[0][ds], Bf, acc[0][kt], 0, 0, 0);
        acc[1][kt] = __builtin_amdgcn_mfma_f32_16x16x32_bf16(sa[1][ds], Bf, acc[1][kt], 0, 0, 0);
        acc[2][kt] = __builtin_amdgcn_mfma_f32_16x16x32_bf16(sa[2][ds], Bf, acc[2][kt], 0, 0, 0);
        acc[3][kt] = __builtin_amdgcn_mfma_f32_16x16x32_bf16(sa[3][ds], Bf, acc[3][kt], 0, 0, 0);
      }
    // epilogue: tanh-weighted score, reduce over l15 (k dim)
#pragma unroll
    for (int i2 = 0; i2 < 4; ++i2) {
      float part[4] = {wls, wls, wls, wls};
#pragma unroll
      for (int kt = 0; kt < 8; ++kt)
#pragma unroll
        for (int r = 0; r < 4; ++r) {
          float e2 = exp2_fast(fmaf(acc[i2][kt][r], C2L, tb[kt]));
          part[r] = fmaf(-w2s[kt], __builtin_amdgcn_rcpf(e2 + 1.0f), part[r]);
        }
#pragma unroll
      for (int r = 0; r < 4; ++r) {
        float v = part[r];
        v += __shfl_xor(v, 1, 16);
        v += __shfl_xor(v, 2, 16);
        v += __shfl_xor(v, 4, 16);
        v += __shfl_xor(v, 8, 16);
        part[r] = v;
      }
      if (l15 == 0) {
        short4v st;
#pragma unroll
        for (int r = 0; r < 4; ++r) st[r] = (short)(fbits(part[r]) >> 16);
        *(short4v*)&scl[i2][j0 + quad * 4] = st;
      }
    }
  }
  __syncthreads();

  // -------- phase B: softmax numerators + row sums (wave per i-row) ------
  {
    int i = t >> 6, jl = t & 63;
    short4v s4 = *(const short4v*)&scl[i][jl * 4];
    const float SEXP = 0.014426950408889634f;  // log2(e)/100
    float pv[4], ps = 0.0f;
#pragma unroll
    for (int u = 0; u < 4; ++u) {
      float p = exp2_fast(bf2f((unsigned short)s4[u]) * SEXP);
      float pt; { unsigned int tb_ = fbits(p) & 0xFFFF0000u; __builtin_memcpy(&pt, &tb_, 4); }
      pv[u] = pt; ps += pt;
    }
    int2v w0;
    w0[0] = (int)pack2(pv[1], pv[0]);
    w0[1] = (int)pack2(pv[3], pv[2]);
    *(int2v*)&pl[i][jl * 4] = w0;
    for (int off = 32; off; off >>= 1) ps += __shfl_xor(ps, off, 64);
    if (lane == 0) rinv[i] = 1.0f / ps;
  }
  __syncthreads();

  // -------- phase C: agg = (P @ X) * rinv via MFMA (4 waves x 2 d-tiles) --
  {
    f32x4 aw0 = {0.f, 0.f, 0.f, 0.f}, aw1 = {0.f, 0.f, 0.f, 0.f};
    int d0 = wave * 32 + l15;
    const bf* xtb = XbfT + (size_t)b * 32768;
#pragma unroll
    for (int ks = 0; ks < 8; ++ks) {
      short8 af = *(const short8*)&pl[l15][ks * 32 + quad * 8];
      short8 b0 = *(const short8*)(xtb + (size_t)d0 * 256 + ks * 32 + quad * 8);
      short8 b1 = *(const short8*)(xtb + (size_t)(d0 + 16) * 256 + ks * 32 + quad * 8);
      aw0 = __builtin_amdgcn_mfma_f32_16x16x32_bf16(af, b0, aw0, 0, 0, 0);
      aw1 = __builtin_amdgcn_mfma_f32_16x16x32_bf16(af, b1, aw1, 0, 0, 0);
    }
    if (quad == 0) {
#pragma unroll
      for (int r = 0; r < 4; ++r) {
        float ri = rinv[r];
        aggl[r][d0] = aw0[r] * ri;
        aggl[r][d0 + 16] = aw1[r] * ri;
      }
    }
  }
  __syncthreads();

  // -------- phase D: heads + BN + SELU (4 i rows) --------
  {
    int k = t & 127, ih = t >> 7;
    float o1[2], o2[2];
#pragma unroll
    for (int m = 0; m < 2; ++m) { o1[m] = 0.0f; o2[m] = 0.0f; }
    const f32x4* wa = (const f32x4*)(WpaT + k * 128);
    const f32x4* wn = (const f32x4*)(WpnT + k * 128);
#pragma unroll 2
    for (int c = 0; c < 32; ++c) {
      f32x4 a4 = wa[c], n4 = wn[c];
#pragma unroll
      for (int m = 0; m < 2; ++m) {
        int i = ih * 2 + m;
        f32x4 g4 = *(const f32x4*)&aggl[i][c * 4];
        f32x4 x4 = *(const f32x4*)&xif[i][c * 4];
        o1[m] += g4[0] * a4[0] + g4[1] * a4[1] + g4[2] * a4[2] + g4[3] * a4[3];
        o2[m] += x4[0] * n4[0] + x4[1] * n4[1] + x4[2] * n4[2] + x4[3] * n4[3];
      }
    }
    float gk = gamma[k], bk = beta[k], b1 = bpa[k], b2 = bpn[k];
    const float SC = 1.0507009873554805f, AL = 1.6732632423543772f;
#pragma unroll
    for (int m = 0; m < 2; ++m) {
      float v = o1[m] + b1 + o2[m] + b2;
      v = v * 0.99999500003749969f * gk + bk;
      v = (v > 0.0f) ? SC * v : SC * AL * (__expf(v) - 1.0f);
      int gi = ibase + ih * 2 + m;
      size_t oo = (gi < 128) ? ((size_t)(b * 128 + gi) * 128 + k)
                             : (size_t)131072 + ((size_t)(b * 128 + gi - 128) * 128 + k);
      dout[oo] = v;
    }
  }

  // -------- phase E (ig==0 blocks): master node output (overlay on wfrag) -
  if (ig == 0) {
    float* attM = (float*)smem;                   // 1024
    float* redwM = (float*)(smem + 1024);         // 16
    float (*aggpM)[128] = (float(*)[128])(smem + 1088);  // 8192
    float* aggmM = (float*)(smem + 9280);         // 512
    __syncthreads();
    float p = __expf(sM[b * 256 + t] * 0.01f);
    float s = p;
    for (int off = 32; off; off >>= 1) s += __shfl_xor(s, off, 64);
    if ((t & 63) == 0) redwM[t >> 6] = s;
    __syncthreads();
    attM[t] = p / (redwM[0] + redwM[1] + redwM[2] + redwM[3]);
    __syncthreads();
    {
      int dg = t & 15, jl = t >> 4;
      float part[8];
#pragma unroll
      for (int u = 0; u < 8; ++u) part[u] = 0.0f;
      for (int j = jl; j < 256; j += 16) {
        float a = attM[j];
        short8 xr = *(const short8*)(Xbf + ((size_t)b * 256 + j) * 128 + dg * 8);
#pragma unroll
        for (int u = 0; u < 8; ++u) part[u] = fmaf(a, bf2f((unsigned short)xr[u]), part[u]);
      }
#pragma unroll
      for (int u = 0; u < 8; ++u) aggpM[jl][dg * 8 + u] = part[u];
    }
    __syncthreads();
    if (t < 128) {
      float s2 = 0.0f;
#pragma unroll
      for (int j = 0; j < 16; ++j) s2 += aggpM[j][t];
      aggmM[t] = s2;
    }
    __syncthreads();
    if (t < 128) {
      int k = t;
      float a1 = 0.0f, a2 = 0.0f;
      const f32x4* wa = (const f32x4*)(WpaMT + k * 128);
      const f32x4* wn = (const f32x4*)(WpnMT + k * 128);
#pragma unroll 4
      for (int c = 0; c < 32; ++c) {
        f32x4 w4 = wa[c], n4 = wn[c];
        f32x4 g4 = *(const f32x4*)&aggmM[c * 4];
        f32x4 m4 = *(const f32x4*)(masterf + b * 128 + c * 4);
        a1 += g4[0] * w4[0] + g4[1] * w4[1] + g4[2] * w4[2] + g4[3] * w4[3];
        a2 += m4[0] * n4[0] + m4[1] * n4[1] + m4[2] * n4[2] + m4[3] * n4[3];
      }
      dout[262144 + b * 128 + k] = a1 + bpaM[k] + a2 + bpnM[k];
    }
  }
}

extern "C" void kernel_launch(void* const* d_in, const int* in_sizes, int n_in,
                              void* d_out, int out_size, void* d_ws, size_t ws_size,
                              hipStream_t stream) {
  const float* x1  = (const float*)d_in[0];
  const float* x2  = (const float*)d_in[1];
  const float* Wt1 = (const float*)d_in[2];
  const float* bt1 = (const float*)d_in[3];
  const float* Wt2 = (const float*)d_in[4];
  const float* bt2 = (const float*)d_in[5];
  const float* Wa  = (const float*)d_in[6];
  const float* ba  = (const float*)d_in[7];
  const float* WaM = (const float*)d_in[8];
  const float* baM = (const float*)d_in[9];
  const float* w11 = (const float*)d_in[10];
  const float* w22 = (const float*)d_in[11];
  const float* w12 = (const float*)d_in[12];
  const float* wM  = (const float*)d_in[13];
  const float* Wpa = (const float*)d_in[14];
  const float* bpa = (const float*)d_in[15];
  const float* Wpn = (const float*)d_in[16];
  const float* bpn = (const float*)d_in[17];
  const float* WpaM = (const float*)d_in[18];
  const float* bpaM = (const float*)d_in[19];
  const float* WpnM = (const float*)d_in[20];
  const float* bpnM = (const float*)d_in[21];
  const float* gamma = (const float*)d_in[22];
  const float* beta  = (const float*)d_in[23];

  char* ws = (char*)d_ws;
  bf*    Xbf    = (bf*)(ws);                    // 524288
  bf*    XbfT   = (bf*)(ws + 524288);           // 524288
  bf*    WaFrag = (bf*)(ws + 1048576);          // 32768
  float* WtT1   = (float*)(ws + 1081344);       // 65536
  float* WtT2   = (float*)(ws + 1146880);       // 65536
  float* WaMT   = (float*)(ws + 1212416);       // 65536
  float* WpaT   = (float*)(ws + 1277952);       // 65536
  float* WpnT   = (float*)(ws + 1343488);       // 65536
  float* WpaMT  = (float*)(ws + 1409024);       // 65536
  float* WpnMT  = (float*)(ws + 1474560);       // 65536
  float* masterf= (float*)(ws + 1540096);       // 4096
  float* sM     = (float*)(ws + 1544192);       // 8192 (total 1552384)

  float* outp = (float*)d_out;

  k_prep<<<512, 256, 0, stream>>>(Wa, Wt1, Wt2, WaM, Wpa, Wpn, WpaM, WpnM,
                                  WaFrag, WtT1, WtT2, WaMT, WpaT, WpnT, WpaMT, WpnMT);
  k_proj<<<128, 256, 0, stream>>>(x1, x2, WtT1, bt1, WtT2, bt2, Xbf, XbfT);
  k_mscore<<<128, 256, 0, stream>>>(Xbf, WaMT, baM, wM, sM, masterf);
  k_fused<<<512, 256, 0, stream>>>(Xbf, XbfT, WaFrag, ba, w11, w22, w12,
                                   WpaT, bpa, WpnT, bpn, gamma, beta,
                                   sM, masterf, WpaMT, bpaM, WpnMT, bpnM, outp);
}

// Round 12
// 174.083 us; speedup vs baseline: 1.0376x; 1.0376x over previous
//
#include <hip/hip_runtime.h>
#include <hip/hip_bf16.h>
#include <cstddef>

typedef short short8 __attribute__((ext_vector_type(8)));
typedef short short4v __attribute__((ext_vector_type(4)));
typedef short short2v __attribute__((ext_vector_type(2)));
typedef int   int2v  __attribute__((ext_vector_type(2)));
typedef int   int4v  __attribute__((ext_vector_type(4)));
typedef float f32x4  __attribute__((ext_vector_type(4)));
typedef __hip_bfloat16 bf;

#define DEV __device__ __forceinline__

DEV float bf2f(unsigned short u) {
  unsigned int x = ((unsigned int)u) << 16;
  float f; __builtin_memcpy(&f, &x, 4); return f;
}
DEV unsigned int fbits(float v) {
  unsigned int u; __builtin_memcpy(&u, &v, 4); return u;
}
// pack two f32 -> one dword of two bf16 (truncation), hi:lo
DEV unsigned int pack2(float hi, float lo) {
  return __builtin_amdgcn_perm(fbits(hi), fbits(lo), 0x07060302u);
}
DEV float exp2_fast(float x) {
#if __has_builtin(__builtin_amdgcn_exp2f)
  return __builtin_amdgcn_exp2f(x);
#else
  return exp2f(x);
#endif
}
DEV float fast_tanh(float x) {
  float e2 = __expf(2.0f * x);
  return 1.0f - 2.0f * __builtin_amdgcn_rcpf(e2 + 1.0f);
}

// ============ K1: projection -> Xbf + XbfT; blocks 128..135: WaFrag =======
__global__ void __launch_bounds__(256) k_proj(
    const float* __restrict__ x1, const float* __restrict__ x2,
    const float* __restrict__ Wt1, const float* __restrict__ bt1,
    const float* __restrict__ Wt2, const float* __restrict__ bt2,
    const float* __restrict__ Wa,
    bf* __restrict__ Xbf, bf* __restrict__ XbfT, bf* __restrict__ WaFrag) {
  int t = threadIdx.x;
  if (blockIdx.x >= 128) {
    // WaFrag permute: fragment order chunk c=(kt*4+ds)*64+lane, elem u 0..7
    int base = (blockIdx.x - 128) * 2048 + t * 8;
#pragma unroll
    for (int u = 0; u < 8; ++u) {
      int idx = base + u;
      int c = idx >> 3, uu = idx & 7;
      int kt = c >> 8, ds = (c >> 6) & 3, L = c & 63;
      int l15 = L & 15, q = L >> 4;
      int d = ds * 32 + q * 8 + uu;
      int k = kt * 16 + l15;
      WaFrag[idx] = __float2bfloat16(Wa[d * 128 + k]);
    }
    return;
  }
  int b = blockIdx.x >> 4, g = blockIdx.x & 15;
  int ibase = g * 16;
  bool side1 = ibase < 128;
  const float* W = side1 ? Wt1 : Wt2;
  const float* bt = side1 ? bt1 : bt2;
  const float* xs = side1 ? (x1 + ((size_t)b * 128 + ibase) * 128)
                          : (x2 + ((size_t)b * 128 + (ibase - 128)) * 128);
  __shared__ float rowz[16][128];
  {
    int i = t >> 4, dg = t & 15;
    const f32x4* p = (const f32x4*)(xs + i * 128 + dg * 8);
    *(f32x4*)&rowz[i][dg * 8] = p[0];
    *(f32x4*)&rowz[i][dg * 8 + 4] = p[1];
  }
  __syncthreads();
  int k = t & 127, ih = t >> 7;
  float acc[8];
  float bb = bt[k];
#pragma unroll
  for (int m = 0; m < 8; ++m) acc[m] = bb;
  // direct row-major W: thread-k coalesced scalar loads
#pragma unroll 4
  for (int d = 0; d < 128; ++d) {
    float wv = W[d * 128 + k];
#pragma unroll
    for (int m = 0; m < 8; ++m) acc[m] = fmaf(rowz[ih * 8 + m][d], wv, acc[m]);
  }
#pragma unroll
  for (int m = 0; m < 8; ++m)
    Xbf[((size_t)b * 256 + ibase + ih * 8 + m) * 128 + k] = __float2bfloat16(acc[m]);
  int4v tv;
  tv[0] = (int)pack2(acc[1], acc[0]);
  tv[1] = (int)pack2(acc[3], acc[2]);
  tv[2] = (int)pack2(acc[5], acc[4]);
  tv[3] = (int)pack2(acc[7], acc[6]);
  *(int4v*)(XbfT + (size_t)b * 32768 + (size_t)k * 256 + ibase + ih * 8) = tv;
}

// ============ K2: master mean + attention scores sM[b,n] ==================
__global__ void __launch_bounds__(256) k_mscore(
    const bf* __restrict__ Xbf,
    const float* __restrict__ WaM, const float* __restrict__ baM,
    const float* __restrict__ wM, float* __restrict__ sM,
    float* __restrict__ masterf) {
  int b = blockIdx.x >> 4, g = blockIdx.x & 15;
  int nbase = g * 16;
  int t = threadIdx.x;
  __shared__ float red[16][128];
  __shared__ float masterv[128];
  __shared__ float z[16][128];
  {
    int dg = t & 15, rl = t >> 4;
    float part[8];
#pragma unroll
    for (int u = 0; u < 8; ++u) part[u] = 0.0f;
    for (int r = rl; r < 256; r += 16) {
      short8 xr = *(const short8*)(Xbf + ((size_t)b * 256 + r) * 128 + dg * 8);
#pragma unroll
      for (int u = 0; u < 8; ++u) part[u] += bf2f((unsigned short)xr[u]);
    }
#pragma unroll
    for (int u = 0; u < 8; ++u) red[rl][dg * 8 + u] = part[u];
  }
  __syncthreads();
  if (t < 128) {
    float s = 0.0f;
#pragma unroll
    for (int j = 0; j < 16; ++j) s += red[j][t];
    s *= (1.0f / 256.0f);
    masterv[t] = s;
    if (g == 0) masterf[b * 128 + t] = s;
  }
  __syncthreads();
  {
    int n = t >> 4, dg = t & 15;
    short8 xr = *(const short8*)(Xbf + ((size_t)b * 256 + nbase + n) * 128 + dg * 8);
#pragma unroll
    for (int u = 0; u < 8; ++u)
      z[n][dg * 8 + u] = bf2f((unsigned short)xr[u]) * masterv[dg * 8 + u];
  }
  __syncthreads();
  int k = t & 127, nh = t >> 7;
  float acc[8];
  float bb = baM[k];
#pragma unroll
  for (int m = 0; m < 8; ++m) acc[m] = bb;
#pragma unroll 4
  for (int d = 0; d < 128; ++d) {
    float wv = WaM[d * 128 + k];
#pragma unroll
    for (int m = 0; m < 8; ++m) acc[m] = fmaf(z[nh * 8 + m][d], wv, acc[m]);
  }
  float wk = wM[k];
  __syncthreads();
#pragma unroll
  for (int m = 0; m < 8; ++m) red[nh * 8 + m][k] = fast_tanh(acc[m]) * wk;
  __syncthreads();
  int n2 = t >> 4, kl = t & 15;
  float s = 0.0f;
#pragma unroll
  for (int c = 0; c < 8; ++c) s += red[n2][kl + c * 16];
  s += __shfl_xor(s, 1, 16);
  s += __shfl_xor(s, 2, 16);
  s += __shfl_xor(s, 4, 16);
  s += __shfl_xor(s, 8, 16);
  if (kl == 0) sM[b * 256 + nbase + n2] = s;
}

// ============ K3: fused scores + softmax + agg + heads (+ master out) =====
// grid = 8b x 64ig = 512 blocks, 256 thr (4 waves). Block: 4 i x 256 j.
// jt loop UNROLLED: lets the scheduler hoist wv/Afm loads and overlap the
// transcendental epilogue of jt with the MFMA stream of jt+1.
__global__ void __launch_bounds__(256, 2) k_fused(
    const bf* __restrict__ Xbf, const bf* __restrict__ XbfT,
    const bf* __restrict__ WaFrag,
    const float* __restrict__ ba, const float* __restrict__ w11,
    const float* __restrict__ w22, const float* __restrict__ w12,
    const float* __restrict__ Wpa, const float* __restrict__ bpa,
    const float* __restrict__ Wpn, const float* __restrict__ bpn,
    const float* __restrict__ gamma, const float* __restrict__ beta,
    const float* __restrict__ sM, const float* __restrict__ masterf,
    const float* __restrict__ WpaM, const float* __restrict__ bpaM,
    const float* __restrict__ WpnM, const float* __restrict__ bpnM,
    float* __restrict__ dout) {
  int b = blockIdx.x >> 6, ig = blockIdx.x & 63;
  int ibase = ig * 4;
  int t = threadIdx.x, wave = t >> 6, lane = t & 63, l15 = lane & 15, quad = lane >> 4;

  // hand-carved LDS (49,728 B): wfrag region reused by phase E overlay
  __shared__ __align__(16) char smem[49728];
  unsigned short* wfrag = (unsigned short*)smem;                       // 32768
  float (*xif)[132] = (float(*)[132])(smem + 32768);                   // 2112
  unsigned short (*scl)[264] = (unsigned short(*)[264])(smem + 34880); // 2112
  unsigned short (*pl)[264] = (unsigned short(*)[264])(smem + 36992);  // 8448
  float (*aggl)[132] = (float(*)[132])(smem + 45440);                  // 4224
  float* rinv = (float*)(smem + 49664);                                // 64

  // stage Wa fragments (coalesced 16 B/lane)
#pragma unroll
  for (int c = 0; c < 8; ++c) {
    int idx = c * 256 + t;
    *(short8*)&wfrag[idx * 8] = *(const short8*)(WaFrag + (size_t)idx * 8);
  }
  // stage x_i rows unpacked to f32 (4 rows x 128)
  {
    int ii = t >> 6, dg = t & 63;
    short2v xr = *(const short2v*)(Xbf + ((size_t)(b * 256 + ibase + ii)) * 128 + dg * 2);
    xif[ii][dg * 2] = bf2f((unsigned short)xr[0]);
    xif[ii][dg * 2 + 1] = bf2f((unsigned short)xr[1]);
  }
  // zero MFMA pad: pl rows 4..15 (cols 0..255) and rinv[4..15]
  {
    int4v zz = {0, 0, 0, 0};
    int r0 = 4 + (t >> 5), c0 = (t & 31) * 8;
    *(int4v*)&pl[r0][c0] = zz;
    if (t < 128) *(int4v*)&pl[4 + ((t + 256) >> 5)][((t + 256) & 31) * 8] = zz;
    if (t < 12) rinv[4 + t] = 0.0f;
  }

  bool side1 = ig < 32;
  const float C2L = 2.8853900817779268f;  // 2*log2(e)
  float tb[8];
#pragma unroll
  for (int kt = 0; kt < 8; ++kt) tb[kt] = ba[kt * 16 + l15] * C2L;
  __syncthreads();

  // -------- phase A: scores for 4 i x 256 j (wave owns 16 j per pass) ----
#pragma unroll
  for (int jt = 0; jt < 4; ++jt) {
    int j0 = jt * 64 + wave * 16;
    const float* wv = side1 ? (jt < 2 ? w11 : w12) : (jt < 2 ? w12 : w22);
    float w2s[8], wls = 0.0f;
#pragma unroll
    for (int kt = 0; kt < 8; ++kt) {
      float w = wv[kt * 16 + l15];
      w2s[kt] = 2.0f * w;
      wls += w;
    }
    float Afm[4][8];
#pragma unroll
    for (int ds = 0; ds < 4; ++ds) {
      short8 a = *(const short8*)(Xbf + ((size_t)(b * 256 + j0 + l15)) * 128 + ds * 32 + quad * 8);
#pragma unroll
      for (int u = 0; u < 8; ++u) Afm[ds][u] = bf2f((unsigned short)a[u]);
    }
    // pack scaled-A for all 4 i
    short8 sa[4][4];
#pragma unroll
    for (int i2 = 0; i2 < 4; ++i2)
#pragma unroll
      for (int ds = 0; ds < 4; ++ds) {
        const f32x4* xp = (const f32x4*)&xif[i2][ds * 32 + quad * 8];
        f32x4 x0 = xp[0], x1 = xp[1];
        int4v pk;
        pk[0] = (int)pack2(Afm[ds][1] * x0[1], Afm[ds][0] * x0[0]);
        pk[1] = (int)pack2(Afm[ds][3] * x0[3], Afm[ds][2] * x0[2]);
        pk[2] = (int)pack2(Afm[ds][5] * x1[1], Afm[ds][4] * x1[0]);
        pk[3] = (int)pack2(Afm[ds][7] * x1[3], Afm[ds][6] * x1[2]);
        sa[i2][ds] = __builtin_bit_cast(short8, pk);
      }
    // MFMA: each Bf read feeds 4 independent accumulation chains
    f32x4 acc[4][8];
#pragma unroll
    for (int i2 = 0; i2 < 4; ++i2)
#pragma unroll
      for (int kt = 0; kt < 8; ++kt) { f32x4 z = {0.f, 0.f, 0.f, 0.f}; acc[i2][kt] = z; }
#pragma unroll
    for (int kt = 0; kt < 8; ++kt)
#pragma unroll
      for (int ds = 0; ds < 4; ++ds) {
        short8 Bf = *(const short8*)&wfrag[((kt * 4 + ds) * 64 + lane) * 8];
        acc[0][kt] = __builtin_amdgcn_mfma_f32_16x16x32_bf16(sa[0][ds], Bf, acc[0][kt], 0, 0, 0);
        acc[1][kt] = __builtin_amdgcn_mfma_f32_16x16x32_bf16(sa[1][ds], Bf, acc[1][kt], 0, 0, 0);
        acc[2][kt] = __builtin_amdgcn_mfma_f32_16x16x32_bf16(sa[2][ds], Bf, acc[2][kt], 0, 0, 0);
        acc[3][kt] = __builtin_amdgcn_mfma_f32_16x16x32_bf16(sa[3][ds], Bf, acc[3][kt], 0, 0, 0);
      }
    // epilogue: tanh-weighted score, reduce over l15 (k dim)
#pragma unroll
    for (int i2 = 0; i2 < 4; ++i2) {
      float part[4] = {wls, wls, wls, wls};
#pragma unroll
      for (int kt = 0; kt < 8; ++kt)
#pragma unroll
        for (int r = 0; r < 4; ++r) {
          float e2 = exp2_fast(fmaf(acc[i2][kt][r], C2L, tb[kt]));
          part[r] = fmaf(-w2s[kt], __builtin_amdgcn_rcpf(e2 + 1.0f), part[r]);
        }
#pragma unroll
      for (int r = 0; r < 4; ++r) {
        float v = part[r];
        v += __shfl_xor(v, 1, 16);
        v += __shfl_xor(v, 2, 16);
        v += __shfl_xor(v, 4, 16);
        v += __shfl_xor(v, 8, 16);
        part[r] = v;
      }
      if (l15 == 0) {
        short4v st;
#pragma unroll
        for (int r = 0; r < 4; ++r) st[r] = (short)(fbits(part[r]) >> 16);
        *(short4v*)&scl[i2][j0 + quad * 4] = st;
      }
    }
  }
  __syncthreads();

  // -------- phase B: softmax numerators + row sums (wave per i-row) ------
  {
    int i = t >> 6, jl = t & 63;
    short4v s4 = *(const short4v*)&scl[i][jl * 4];
    const float SEXP = 0.014426950408889634f;  // log2(e)/100
    float pv[4], ps = 0.0f;
#pragma unroll
    for (int u = 0; u < 4; ++u) {
      float p = exp2_fast(bf2f((unsigned short)s4[u]) * SEXP);
      float pt; { unsigned int tb_ = fbits(p) & 0xFFFF0000u; __builtin_memcpy(&pt, &tb_, 4); }
      pv[u] = pt; ps += pt;
    }
    int2v w0;
    w0[0] = (int)pack2(pv[1], pv[0]);
    w0[1] = (int)pack2(pv[3], pv[2]);
    *(int2v*)&pl[i][jl * 4] = w0;
    for (int off = 32; off; off >>= 1) ps += __shfl_xor(ps, off, 64);
    if (lane == 0) rinv[i] = 1.0f / ps;
  }
  __syncthreads();

  // -------- phase C: agg = (P @ X) * rinv via MFMA (4 waves x 2 d-tiles) --
  {
    f32x4 aw0 = {0.f, 0.f, 0.f, 0.f}, aw1 = {0.f, 0.f, 0.f, 0.f};
    int d0 = wave * 32 + l15;
    const bf* xtb = XbfT + (size_t)b * 32768;
#pragma unroll
    for (int ks = 0; ks < 8; ++ks) {
      short8 af = *(const short8*)&pl[l15][ks * 32 + quad * 8];
      short8 b0 = *(const short8*)(xtb + (size_t)d0 * 256 + ks * 32 + quad * 8);
      short8 b1 = *(const short8*)(xtb + (size_t)(d0 + 16) * 256 + ks * 32 + quad * 8);
      aw0 = __builtin_amdgcn_mfma_f32_16x16x32_bf16(af, b0, aw0, 0, 0, 0);
      aw1 = __builtin_amdgcn_mfma_f32_16x16x32_bf16(af, b1, aw1, 0, 0, 0);
    }
    if (quad == 0) {
#pragma unroll
      for (int r = 0; r < 4; ++r) {
        float ri = rinv[r];
        aggl[r][d0] = aw0[r] * ri;
        aggl[r][d0 + 16] = aw1[r] * ri;
      }
    }
  }
  __syncthreads();

  // -------- phase D: heads + BN + SELU (4 i rows; direct row-major W) ----
  {
    int k = t & 127, ih = t >> 7;
    float o1[2], o2[2];
#pragma unroll
    for (int m = 0; m < 2; ++m) { o1[m] = 0.0f; o2[m] = 0.0f; }
#pragma unroll 2
    for (int c = 0; c < 32; ++c) {
      f32x4 g40 = *(const f32x4*)&aggl[ih * 2][c * 4];
      f32x4 g41 = *(const f32x4*)&aggl[ih * 2 + 1][c * 4];
      f32x4 x40 = *(const f32x4*)&xif[ih * 2][c * 4];
      f32x4 x41 = *(const f32x4*)&xif[ih * 2 + 1][c * 4];
#pragma unroll
      for (int u = 0; u < 4; ++u) {
        float wav = Wpa[(c * 4 + u) * 128 + k];
        float wnv = Wpn[(c * 4 + u) * 128 + k];
        o1[0] = fmaf(g40[u], wav, o1[0]);
        o1[1] = fmaf(g41[u], wav, o1[1]);
        o2[0] = fmaf(x40[u], wnv, o2[0]);
        o2[1] = fmaf(x41[u], wnv, o2[1]);
      }
    }
    float gk = gamma[k], bk = beta[k], b1 = bpa[k], b2 = bpn[k];
    const float SC = 1.0507009873554805f, AL = 1.6732632423543772f;
#pragma unroll
    for (int m = 0; m < 2; ++m) {
      float v = o1[m] + b1 + o2[m] + b2;
      v = v * 0.99999500003749969f * gk + bk;
      v = (v > 0.0f) ? SC * v : SC * AL * (__expf(v) - 1.0f);
      int gi = ibase + ih * 2 + m;
      size_t oo = (gi < 128) ? ((size_t)(b * 128 + gi) * 128 + k)
                             : (size_t)131072 + ((size_t)(b * 128 + gi - 128) * 128 + k);
      dout[oo] = v;
    }
  }

  // -------- phase E (ig==0 blocks): master node output (overlay on wfrag) -
  if (ig == 0) {
    float* attM = (float*)smem;                   // 1024
    float* redwM = (float*)(smem + 1024);         // 16
    float (*aggpM)[128] = (float(*)[128])(smem + 1088);  // 8192
    float* aggmM = (float*)(smem + 9280);         // 512
    __syncthreads();
    float p = __expf(sM[b * 256 + t] * 0.01f);
    float s = p;
    for (int off = 32; off; off >>= 1) s += __shfl_xor(s, off, 64);
    if ((t & 63) == 0) redwM[t >> 6] = s;
    __syncthreads();
    attM[t] = p / (redwM[0] + redwM[1] + redwM[2] + redwM[3]);
    __syncthreads();
    {
      int dg = t & 15, jl = t >> 4;
      float part[8];
#pragma unroll
      for (int u = 0; u < 8; ++u) part[u] = 0.0f;
      for (int j = jl; j < 256; j += 16) {
        float a = attM[j];
        short8 xr = *(const short8*)(Xbf + ((size_t)b * 256 + j) * 128 + dg * 8);
#pragma unroll
        for (int u = 0; u < 8; ++u) part[u] = fmaf(a, bf2f((unsigned short)xr[u]), part[u]);
      }
#pragma unroll
      for (int u = 0; u < 8; ++u) aggpM[jl][dg * 8 + u] = part[u];
    }
    __syncthreads();
    if (t < 128) {
      float s2 = 0.0f;
#pragma unroll
      for (int j = 0; j < 16; ++j) s2 += aggpM[j][t];
      aggmM[t] = s2;
    }
    __syncthreads();
    if (t < 128) {
      int k = t;
      float a1 = 0.0f, a2 = 0.0f;
#pragma unroll 4
      for (int d = 0; d < 128; ++d) {
        a1 = fmaf(aggmM[d], WpaM[d * 128 + k], a1);
        a2 = fmaf(masterf[b * 128 + d], WpnM[d * 128 + k], a2);
      }
      dout[262144 + b * 128 + k] = a1 + bpaM[k] + a2 + bpnM[k];
    }
  }
}

extern "C" void kernel_launch(void* const* d_in, const int* in_sizes, int n_in,
                              void* d_out, int out_size, void* d_ws, size_t ws_size,
                              hipStream_t stream) {
  const float* x1  = (const float*)d_in[0];
  const float* x2  = (const float*)d_in[1];
  const float* Wt1 = (const float*)d_in[2];
  const float* bt1 = (const float*)d_in[3];
  const float* Wt2 = (const float*)d_in[4];
  const float* bt2 = (const float*)d_in[5];
  const float* Wa  = (const float*)d_in[6];
  const float* ba  = (const float*)d_in[7];
  const float* WaM = (const float*)d_in[8];
  const float* baM = (const float*)d_in[9];
  const float* w11 = (const float*)d_in[10];
  const float* w22 = (const float*)d_in[11];
  const float* w12 = (const float*)d_in[12];
  const float* wM  = (const float*)d_in[13];
  const float* Wpa = (const float*)d_in[14];
  const float* bpa = (const float*)d_in[15];
  const float* Wpn = (const float*)d_in[16];
  const float* bpn = (const float*)d_in[17];
  const float* WpaM = (const float*)d_in[18];
  const float* bpaM = (const float*)d_in[19];
  const float* WpnM = (const float*)d_in[20];
  const float* bpnM = (const float*)d_in[21];
  const float* gamma = (const float*)d_in[22];
  const float* beta  = (const float*)d_in[23];

  char* ws = (char*)d_ws;
  bf*    Xbf    = (bf*)(ws);                    // 524288
  bf*    XbfT   = (bf*)(ws + 524288);           // 524288
  bf*    WaFrag = (bf*)(ws + 1048576);          // 32768
  float* masterf= (float*)(ws + 1081344);       // 4096
  float* sM     = (float*)(ws + 1085440);       // 8192 (total 1093632)

  float* outp = (float*)d_out;

  k_proj<<<136, 256, 0, stream>>>(x1, x2, Wt1, bt1, Wt2, bt2, Wa, Xbf, XbfT, WaFrag);
  k_mscore<<<128, 256, 0, stream>>>(Xbf, WaM, baM, wM, sM, masterf);
  k_fused<<<512, 256, 0, stream>>>(Xbf, XbfT, WaFrag, ba, w11, w22, w12,
                                   Wpa, bpa, Wpn, bpn, gamma, beta,
                                   sM, masterf, WpaM, bpaM, WpnM, bpnM, outp);
}